// Round 8
// baseline (118.973 us; speedup 1.0000x reference)
//
#include <hip/hip_runtime.h>

#define Bb 4
#define Qn 256
#define Kn 1024
#define Hn 128
#define QT 4           // q-rows per fused block
#define CH 8           // h-rows per ekT stage chunk (8*1024*4 = 32 KB)
#define NCH (Hn / CH)  // 16 chunks
#define CKV 64         // k-rows per value stage chunk (64*128*4 = 32 KB)
#define NCKV (Kn / CKV)

// Projections pre-scaled by 2*log2(e) and exponentiated: Eq=2^(s*qp), Ek=2^(s*kp)
// => e^{2(qp+kp)} = Eq*Ek, and tanh(qp+kp) = 1 - 2/(1+Eq*Ek).
constexpr float SCALE = 2.88539008177792681f;  // 2*log2(e)

#if __has_builtin(__builtin_amdgcn_exp2f)
#define EXP2F(x) __builtin_amdgcn_exp2f(x)
#else
#define EXP2F(x) exp2f(x)
#endif
#if __has_builtin(__builtin_amdgcn_rcpf)
#define RCPF(x) __builtin_amdgcn_rcpf(x)
#else
#define RCPF(x) (1.0f / (x))
#endif

// ---------------------------------------------------------------------------
// K1: fused projections. Blocks [0, Bb*Qn/4): query -> Eq (row-major).
// Blocks [Bb*Qn/4, +Bb*Kn/4): key -> EkT (transposed [b,h,k]).
// Both stored as exp2(SCALE * proj).
// ---------------------------------------------------------------------------
__global__ __launch_bounds__(128) void proj_kernel(const float* __restrict__ query,
                                                   const float* __restrict__ key,
                                                   const float* __restrict__ Wq,
                                                   const float* __restrict__ Wk,
                                                   float* __restrict__ eq,
                                                   float* __restrict__ ekT) {
    __shared__ float4 xs[128];  // 4 rows x 32 float4
    const int tid = threadIdx.x;
    const bool isQ = blockIdx.x < (Bb * Qn / 4);
    const int r0 = (isQ ? blockIdx.x : blockIdx.x - Bb * Qn / 4) * 4;
    const float* x = isQ ? query : key;
    const float* W = isQ ? Wq : Wk;

    xs[tid] = ((const float4*)(x + (size_t)r0 * Hn))[tid];
    __syncthreads();
    const float4* W4 = (const float4*)W + (size_t)tid * (Hn / 4);
    float acc0 = 0.f, acc1 = 0.f, acc2 = 0.f, acc3 = 0.f;
#pragma unroll 8
    for (int d = 0; d < Hn / 4; ++d) {
        float4 w = W4[d];
        float4 a0 = xs[d];
        float4 a1 = xs[32 + d];
        float4 a2 = xs[64 + d];
        float4 a3 = xs[96 + d];
        acc0 = fmaf(w.x, a0.x, fmaf(w.y, a0.y, fmaf(w.z, a0.z, fmaf(w.w, a0.w, acc0))));
        acc1 = fmaf(w.x, a1.x, fmaf(w.y, a1.y, fmaf(w.z, a1.z, fmaf(w.w, a1.w, acc1))));
        acc2 = fmaf(w.x, a2.x, fmaf(w.y, a2.y, fmaf(w.z, a2.z, fmaf(w.w, a2.w, acc2))));
        acc3 = fmaf(w.x, a3.x, fmaf(w.y, a3.y, fmaf(w.z, a3.z, fmaf(w.w, a3.w, acc3))));
    }
    if (isQ) {
        eq[(size_t)(r0 + 0) * Hn + tid] = EXP2F(acc0 * SCALE);
        eq[(size_t)(r0 + 1) * Hn + tid] = EXP2F(acc1 * SCALE);
        eq[(size_t)(r0 + 2) * Hn + tid] = EXP2F(acc2 * SCALE);
        eq[(size_t)(r0 + 3) * Hn + tid] = EXP2F(acc3 * SCALE);
    } else {
        const int b = r0 / Kn;
        const int k0 = r0 % Kn;
        float4 res = make_float4(EXP2F(acc0 * SCALE), EXP2F(acc1 * SCALE),
                                 EXP2F(acc2 * SCALE), EXP2F(acc3 * SCALE));
        ((float4*)ekT)[(size_t)(b * Hn + tid) * (Kn / 4) + (k0 >> 2)] = res;
    }
}

// ---------------------------------------------------------------------------
// K2: fused score + softmax + context. Block = 1024 thr, (b, QT=4 q-rows).
// Grid = 256 blocks = 1/CU. vs R7: phases A and C consume global data via
// DOUBLE-BUFFERED LDS staging with async-split (issue next chunk's loads to
// registers BEFORE compute, ds_write after) -> memory latency is hidden
// structurally instead of via (VGPR-capped) compiler prefetch.
// mask skipped: -1e-9*(1-mask) perturbs weights by ~1e-12.
// ---------------------------------------------------------------------------
__global__ __launch_bounds__(1024) void fused_attn_kernel(const float* __restrict__ eq,
                                                          const float* __restrict__ ekT,
                                                          const float* __restrict__ v,
                                                          const float* __restrict__ value,
                                                          float* __restrict__ attn,
                                                          float* __restrict__ ctx) {
    const int tid = threadIdx.x;
    const int q0 = blockIdx.x * QT;
    const int b = blockIdx.y;

    __shared__ __align__(16) float stage[2][CH * Kn];  // 2 x 32 KB (reused in C)
    __shared__ __align__(16) float4 qs4[Hn];           // Eq[q0..q0+3][h]
    __shared__ float vs[Hn];                           // v[h]
    __shared__ __align__(16) float sc[QT][Kn];         // weights (16 KB)
    __shared__ float red[16][QT];                      // per-wave partials
    __shared__ __align__(16) float4 pl[8][QT][Hn / 4]; // ctx partials (16 KB)

    if (tid < Hn) vs[tid] = v[tid];
    if (tid < QT * Hn) {
        const int q = tid >> 7, h = tid & 127;
        ((float*)&qs4[h])[q] = eq[((size_t)b * Qn + q0 + q) * Hn + h];
    }

    const float* ekb = ekT + (size_t)b * Hn * Kn;
    {   // stage ek chunk 0
        const float4* s = (const float4*)ekb;
        float4 tA = s[tid], tB = s[tid + 1024];
        ((float4*)&stage[0][0])[tid] = tA;
        ((float4*)&stage[0][0])[tid + 1024] = tB;
    }
    __syncthreads();

    // ---- phase A: thread = k (tid), 4 q-chains; ek via staged LDS ----
    float a0 = 0.f, a1 = 0.f, a2 = 0.f, a3 = 0.f;
    for (int c = 0; c < NCH; ++c) {
        const int cur = c & 1;
        const bool more = (c + 1 < NCH);
        float4 tA, tB;
        if (more) {  // issue next chunk's loads BEFORE compute (T14 split)
            const float4* s = (const float4*)(ekb + (size_t)(c + 1) * CH * Kn);
            tA = s[tid];
            tB = s[tid + 1024];
        }
        const float* sb = &stage[cur][0];
#pragma unroll
        for (int j = 0; j < CH; ++j) {
            const int h = c * CH + j;
            const float kv = sb[j * Kn + tid];
            const float4 qv = qs4[h];
            const float vh = vs[h];
            float r;
            r = RCPF(fmaf(qv.x, kv, 1.0f)); a0 = fmaf(vh, r, a0);
            r = RCPF(fmaf(qv.y, kv, 1.0f)); a1 = fmaf(vh, r, a1);
            r = RCPF(fmaf(qv.z, kv, 1.0f)); a2 = fmaf(vh, r, a2);
            r = RCPF(fmaf(qv.w, kv, 1.0f)); a3 = fmaf(vh, r, a3);
        }
        if (more) {
            float* db = &stage[cur ^ 1][0];
            ((float4*)db)[tid] = tA;
            ((float4*)db)[tid + 1024] = tB;
        }
        __syncthreads();
    }

    // ---- phase B: softmax (score = V - 2a, shift-invariant -> min-reduce a)
    const int lane = tid & 63, wv = tid >> 6;  // 16 waves
    float m0 = a0, m1 = a1, m2 = a2, m3 = a3;
#pragma unroll
    for (int off = 32; off; off >>= 1) {
        m0 = fminf(m0, __shfl_xor(m0, off));
        m1 = fminf(m1, __shfl_xor(m1, off));
        m2 = fminf(m2, __shfl_xor(m2, off));
        m3 = fminf(m3, __shfl_xor(m3, off));
    }
    if (lane == 0) {
        red[wv][0] = m0; red[wv][1] = m1; red[wv][2] = m2; red[wv][3] = m3;
    }
    __syncthreads();
    m0 = red[0][0]; m1 = red[0][1]; m2 = red[0][2]; m3 = red[0][3];
#pragma unroll
    for (int w = 1; w < 16; ++w) {
        m0 = fminf(m0, red[w][0]); m1 = fminf(m1, red[w][1]);
        m2 = fminf(m2, red[w][2]); m3 = fminf(m3, red[w][3]);
    }
    __syncthreads();  // red reused for sums

    float e0 = EXP2F((m0 - a0) * SCALE);
    float e1 = EXP2F((m1 - a1) * SCALE);
    float e2 = EXP2F((m2 - a2) * SCALE);
    float e3 = EXP2F((m3 - a3) * SCALE);
    float s0 = e0, s1 = e1, s2 = e2, s3 = e3;
#pragma unroll
    for (int off = 32; off; off >>= 1) {
        s0 += __shfl_xor(s0, off);
        s1 += __shfl_xor(s1, off);
        s2 += __shfl_xor(s2, off);
        s3 += __shfl_xor(s3, off);
    }
    if (lane == 0) {
        red[wv][0] = s0; red[wv][1] = s1; red[wv][2] = s2; red[wv][3] = s3;
    }
    __syncthreads();
    s0 = red[0][0]; s1 = red[0][1]; s2 = red[0][2]; s3 = red[0][3];
#pragma unroll
    for (int w = 1; w < 16; ++w) {
        s0 += red[w][0]; s1 += red[w][1]; s2 += red[w][2]; s3 += red[w][3];
    }

    const int k = tid;
    const float w0 = e0 * RCPF(s0);
    const float w1 = e1 * RCPF(s1);
    const float w2 = e2 * RCPF(s2);
    const float w3 = e3 * RCPF(s3);
    sc[0][k] = w0; sc[1][k] = w1; sc[2][k] = w2; sc[3][k] = w3;
    float* arow = attn + ((size_t)b * Qn + q0) * Kn + k;
    arow[0 * Kn] = w0; arow[1 * Kn] = w1; arow[2 * Kn] = w2; arow[3 * Kn] = w3;

    // ---- phase C: context via staged value chunks (same dbuf region) ----
    const float* vbase = value + (size_t)b * Kn * Hn;
    {   // stage value chunk 0 (also acts as the sc-store barrier)
        const float4* s = (const float4*)vbase;
        float4 tA = s[tid], tB = s[tid + 1024];
        __syncthreads();  // ensure all phase-A reads of stage[] and sc writes done
        ((float4*)&stage[0][0])[tid] = tA;
        ((float4*)&stage[0][0])[tid + 1024] = tB;
    }
    __syncthreads();

    const int kc2 = tid >> 7;       // 0..7: within-chunk k-subgroup
    const int cq = (tid >> 5) & 3;  // q row
    const int h4 = tid & 31;        // float4 index over h
    float4 acc = make_float4(0.f, 0.f, 0.f, 0.f);
    for (int c = 0; c < NCKV; ++c) {
        const int cur = c & 1;
        const bool more = (c + 1 < NCKV);
        float4 tA, tB;
        if (more) {
            const float4* s = (const float4*)(vbase + (size_t)(c + 1) * CKV * Hn);
            tA = s[tid];
            tB = s[tid + 1024];
        }
        const float* wr = &sc[cq][c * CKV + kc2 * 8];
        const float4* vl = (const float4*)&stage[cur][(size_t)kc2 * 8 * Hn] + h4;
#pragma unroll
        for (int j = 0; j < 8; ++j) {
            const float wgt = wr[j];
            const float4 vv = vl[(size_t)j * (Hn / 4)];
            acc.x = fmaf(wgt, vv.x, acc.x);
            acc.y = fmaf(wgt, vv.y, acc.y);
            acc.z = fmaf(wgt, vv.z, acc.z);
            acc.w = fmaf(wgt, vv.w, acc.w);
        }
        if (more) {
            float* db = &stage[cur ^ 1][0];
            ((float4*)db)[tid] = tA;
            ((float4*)db)[tid + 1024] = tB;
        }
        __syncthreads();
    }
    pl[kc2][cq][h4] = acc;
    __syncthreads();
    if (tid < QT * Hn / 4) {  // 128 threads
        const int q = tid >> 5, h = tid & 31;
        float4 r0 = pl[0][q][h], r1 = pl[1][q][h], r2 = pl[2][q][h], r3 = pl[3][q][h];
        float4 r4 = pl[4][q][h], r5 = pl[5][q][h], r6 = pl[6][q][h], r7 = pl[7][q][h];
        float4 sum;
        sum.x = ((r0.x + r1.x) + (r2.x + r3.x)) + ((r4.x + r5.x) + (r6.x + r7.x));
        sum.y = ((r0.y + r1.y) + (r2.y + r3.y)) + ((r4.y + r5.y) + (r6.y + r7.y));
        sum.z = ((r0.z + r1.z) + (r2.z + r3.z)) + ((r4.z + r5.z) + (r6.z + r7.z));
        sum.w = ((r0.w + r1.w) + (r2.w + r3.w)) + ((r4.w + r5.w) + (r6.w + r7.w));
        ((float4*)(ctx + ((size_t)b * Qn + q0 + q) * Hn))[h] = sum;
    }
}

// ---------------------------------------------------------------------------
extern "C" void kernel_launch(void* const* d_in, const int* in_sizes, int n_in,
                              void* d_out, int out_size, void* d_ws, size_t ws_size,
                              hipStream_t stream) {
    const float* query = (const float*)d_in[0];  // (4,256,128)
    const float* key = (const float*)d_in[1];    // (4,1024,128)
    const float* value = (const float*)d_in[2];  // (4,1024,128)
    // d_in[3] = mask: unused (NEG_MASK_SCALE = -1e-9 -> effect ~1e-12)
    const float* Wq = (const float*)d_in[4];
    const float* Wk = (const float*)d_in[5];
    const float* v = (const float*)d_in[6];

    float* out = (float*)d_out;
    float* attn = out;                        // B*Q*K floats
    float* ctx = out + (size_t)Bb * Qn * Kn;  // B*Q*H floats

    float* ws = (float*)d_ws;
    float* eq = ws;             // 131072 floats: exp2(SCALE*qp)
    float* ekT = ws + 131072;   // 524288 floats: exp2(SCALE*kp), [b,h,k]

    proj_kernel<<<dim3(Bb * Qn / 4 + Bb * Kn / 4), dim3(128), 0, stream>>>(
        query, key, Wq, Wk, eq, ekT);
    fused_attn_kernel<<<dim3(Qn / QT, Bb), dim3(1024), 0, stream>>>(
        eq, ekT, v, value, attn, ctx);
}